// Round 2
// baseline (1440.647 us; speedup 1.0000x reference)
//
#include <hip/hip_runtime.h>
#include <cmath>

#define HID 51
#define BATCH 256
#define BLK 1024     // 16 waves
#define NR 204       // 4*HID gate rows per matrix

typedef _Float16 half2_t __attribute__((ext_vector_type(2)));

// One block per batch element (grid = 256 = #CUs). Two barriers per tick,
// ONE dot row per lane (1021 rows over 1024 lanes):
//   tid [0,204):    L0 Whh row g          . h0(t-1)   -> pG[0][g]   (lp=0)
//   tid [204,408):  L1 Whh row g          . h1(t-1)   -> pG[1][g]   (lp=1)
//   tid [408,612):  L1 Wih row g          . h0(t)     -> pG[2][g]   (lp=1)
//   tid [612,816):  L2 Whh row g          . h2(t-1)   -> pG[3][g]   (lp=2)
//   tid [816,1020): L2 Wih row g          . h1(t)     -> pG[4][g]   (lp=2)
//   tid 1020:       Wl . h2(t) + bl -> obuf ring                    (lp=3)
// Layer l processes timestep t = tau - l (skew 1/tick). Phase A reads the
// h rows written in the previous tick's phase B (barrier-separated), does
// 26 fdot2 against the lane's resident 26-VGPR weight row, writes one
// float partial. Phase B: cell wave per layer (wave l, lanes 0..50, SIMD l)
// combines Whh+Wih partials (+x term for L0), runs the cell, writes h as
// fp16 (ds_write_b16; pads stay zero). Wave 15 flushes the output ring
// 64-wide every 64 ticks. Per-lane weight footprint is 26 VGPRs, so
// nothing can spill; per-SIMD dot issue is 4 waves x 26 insts.

__device__ __forceinline__ float fsig(float v) {
    return __builtin_amdgcn_rcpf(1.f + __expf(-v));
}
__device__ __forceinline__ float ftanh(float v) {
    const float e = __expf(2.f * v);                 // inf-safe
    return fmaf(-2.f, __builtin_amdgcn_rcpf(e + 1.f), 1.f);
}

__attribute__((amdgpu_waves_per_eu(4, 4)))
__global__ __launch_bounds__(BLK)
void lstm3_kernel(const float* __restrict__ x,
                  const float* __restrict__ Wih1, const float* __restrict__ Whh1,
                  const float* __restrict__ bih1, const float* __restrict__ bhh1,
                  const float* __restrict__ Wih,  const float* __restrict__ Whh,
                  const float* __restrict__ bih,  const float* __restrict__ bhh,
                  const float* __restrict__ Wl,   const float* __restrict__ bl,
                  float* __restrict__ out, int T)
{
    const int b    = blockIdx.x;
    const int tid  = threadIdx.x;
    const int wave = tid >> 6;
    const int lane = tid & 63;

    __shared__ __align__(16) float xbuf[2048];
    __shared__ __align__(16) int   hrow[3][32];      // h as fp16 pairs, 128B rows
    __shared__ __align__(16) float pG[5][NR];        // gate partials, [gate*51+u]
    __shared__ __align__(16) float obuf[128];        // output ring (2 x 64)

    for (int i = tid; i < T; i += BLK) xbuf[i] = x[(size_t)b * T + i];
    if (tid < 96) ((int*)hrow)[tid] = 0;             // h = 0 incl. pads

    // ---------------- phase-A role: one dot row per lane ----------------
    const float* wsrc = nullptr;
    int srcrow = 0, lp = 0, m = 0, gg = 0;
    if (tid < 204)        { gg = tid;       wsrc = Whh1 + (size_t)gg * HID;        srcrow = 0; lp = 0; m = 0; }
    else if (tid < 408)   { gg = tid - 204; wsrc = Whh  + (size_t)gg * HID;        srcrow = 1; lp = 1; m = 1; }
    else if (tid < 612)   { gg = tid - 408; wsrc = Wih  + (size_t)gg * HID;        srcrow = 0; lp = 1; m = 2; }
    else if (tid < 816)   { gg = tid - 612; wsrc = Whh  + (size_t)(NR + gg) * HID; srcrow = 2; lp = 2; m = 3; }
    else if (tid < 1020)  { gg = tid - 816; wsrc = Wih  + (size_t)(NR + gg) * HID; srcrow = 1; lp = 2; m = 4; }
    else if (tid == 1020) { wsrc = Wl;                                             srcrow = 2; lp = 3; m = 5; }

    half2_t w2[26];
    #pragma unroll
    for (int j = 0; j < 26; ++j) w2[j] = half2_t{(_Float16)0.f, (_Float16)0.f};
    if (wsrc) {
        #pragma unroll
        for (int j = 0; j < 25; ++j)
            w2[j] = half2_t{(_Float16)wsrc[2 * j], (_Float16)wsrc[2 * j + 1]};
        w2[25] = half2_t{(_Float16)wsrc[50], (_Float16)0.f};
    }
    const int4* hsrc = (const int4*)&hrow[srcrow][0];
    float* dst = (m < 5) ? &pG[m][gg] : nullptr;
    const float obias = (m == 5) ? bl[0] : 0.f;

    // ---------------- phase-B role: cell wave per layer ----------------
    const int cl = wave, cu = lane;
    const bool is_cell = (wave < 3) && (lane < HID);
    float bias4[4] = {0.f, 0.f, 0.f, 0.f};
    float wx4[4]   = {0.f, 0.f, 0.f, 0.f};
    float c_state  = 0.f;
    if (is_cell) {
        #pragma unroll
        for (int k = 0; k < 4; ++k) {
            const int g = k * HID + cu;
            if (cl == 0) { bias4[k] = bih1[g] + bhh1[g]; wx4[k] = Wih1[g]; }
            else         { const int q = (cl - 1) * NR + g; bias4[k] = bih[q] + bhh[q]; }
        }
    }

    __syncthreads();

    const int TICKS = T + 3;
    for (int tau = 0; tau < TICKS; ++tau) {
        // ---------------- phase A: all dot rows ----------------
        const int ta = tau - lp;
        if (wsrc && (unsigned)ta < (unsigned)T) {
            int4 hv[7];
            #pragma unroll
            for (int k = 0; k < 7; ++k) hv[k] = hsrc[k];     // broadcast reads
            const half2_t* hh = (const half2_t*)hv;
            float a0 = 0.f, a1 = 0.f;
            #pragma unroll
            for (int j = 0; j < 26; ++j) {
                if (j & 1) a1 = __builtin_amdgcn_fdot2(w2[j], hh[j], a1, false);
                else       a0 = __builtin_amdgcn_fdot2(w2[j], hh[j], a0, false);
            }
            if (m < 5) *dst = a0 + a1;
            else       obuf[ta & 127] = a0 + a1 + obias;     // lane 1020 only
        }
        __syncthreads();
        // ---------------- phase B: cells + flush ----------------
        if (is_cell) {
            const int t = tau - cl;
            if ((unsigned)t < (unsigned)T) {
                const float* pW = pG[cl == 0 ? 0 : (cl == 1 ? 1 : 3)];
                float gi  = bias4[0] + pW[cu];
                float gf  = bias4[1] + pW[HID + cu];
                float gg_ = bias4[2] + pW[2 * HID + cu];
                float go  = bias4[3] + pW[3 * HID + cu];
                if (cl == 0) {
                    const float xv = xbuf[t];                // broadcast
                    gi  = fmaf(wx4[0], xv, gi);
                    gf  = fmaf(wx4[1], xv, gf);
                    gg_ = fmaf(wx4[2], xv, gg_);
                    go  = fmaf(wx4[3], xv, go);
                } else {
                    const float* pI = pG[cl == 1 ? 2 : 4];
                    gi  += pI[cu];
                    gf  += pI[HID + cu];
                    gg_ += pI[2 * HID + cu];
                    go  += pI[3 * HID + cu];
                }
                const float c = fmaf(fsig(gf), c_state, fsig(gi) * ftanh(gg_));
                c_state = c;
                ((_Float16*)&hrow[cl][0])[cu] = (_Float16)(fsig(go) * ftanh(c));
            }
        } else if (wave == 15 && (tau & 63) == 2 && tau >= 66) {
            // out(t) hits obuf at tick t+3; block [t0, t0+63] complete by here
            const int t0 = tau - 66;                         // multiple of 64
            out[(size_t)b * T + t0 + lane] = obuf[(t0 & 64) + lane];
        }
        __syncthreads();
    }
}

extern "C" void kernel_launch(void* const* d_in, const int* in_sizes, int n_in,
                              void* d_out, int out_size, void* d_ws, size_t ws_size,
                              hipStream_t stream) {
    const float* x    = (const float*)d_in[0];
    const float* Wih1 = (const float*)d_in[1];
    const float* Whh1 = (const float*)d_in[2];
    const float* bih1 = (const float*)d_in[3];
    const float* bhh1 = (const float*)d_in[4];
    const float* Wih  = (const float*)d_in[5];
    const float* Whh  = (const float*)d_in[6];
    const float* bih  = (const float*)d_in[7];
    const float* bhh  = (const float*)d_in[8];
    const float* Wl   = (const float*)d_in[9];
    const float* bl   = (const float*)d_in[10];
    float* out = (float*)d_out;

    const int T = in_sizes[0] / BATCH;   // 2048 (flush assumes T % 64 == 0)
    lstm3_kernel<<<BATCH, BLK, 0, stream>>>(x, Wih1, Whh1, bih1, bhh1,
                                            Wih, Whh, bih, bhh, Wl, bl, out, T);
}